// Round 16
// baseline (785.376 us; speedup 1.0000x reference)
//
#include <hip/hip_runtime.h>
#include <hip/hip_bf16.h>
#include <hip/hip_cooperative_groups.h>

namespace cg = cooperative_groups;

#define N_NODES 50000
#define N_EDGES 500000
#define HDIM 128
#define HEADS 3
#define BB 512
#define LL 10
#define NEG_SLOPE 0.2f

typedef __hip_bfloat16 bf16;
typedef unsigned char fp8t;
typedef __bf16 v8bf __attribute__((ext_vector_type(8)));
typedef float f32x4 __attribute__((ext_vector_type(4)));

#define SCAN_TILE 2048
#define SCAN_NB ((N_NODES + SCAN_TILE - 1)/SCAN_TILE)   // 25
#define COOP_NB 1024
#define COOP_THR (COOP_NB*256)

// ---------------- cooperative prologue: CSR build + mark + list + wt + cvt ----

__global__ __launch_bounds__(256) void k_csr(const int* __restrict__ e_src,
                                             const int* __restrict__ e_dst,
                                             const int* __restrict__ nid,
                                             int* __restrict__ cnt,
                                             int* __restrict__ bsum,
                                             int* __restrict__ offs,
                                             int* __restrict__ csr,
                                             unsigned char* __restrict__ mark,
                                             int* __restrict__ mlist,
                                             int* __restrict__ mcnt,
                                             const float* __restrict__ W1,
                                             const float* __restrict__ W2,
                                             bf16* __restrict__ wt1,
                                             bf16* __restrict__ wt2,
                                             const float* __restrict__ nf,
                                             bf16* __restrict__ nfb){
  cg::grid_group grid = cg::this_grid();
  int tid = threadIdx.x, bid = blockIdx.x;
  int g = bid*256 + tid;
  __shared__ int ws[4];

  // phase 0: zero cnt, mark, mcnt
  for(int i = g; i < N_NODES; i += COOP_THR) cnt[i] = 0;
  for(int i = g; i < (N_NODES+3)/4; i += COOP_THR) ((int*)mark)[i] = 0;
  if(g == 0) mcnt[0] = 0;
  grid.sync();

  // phase 1: histogram of dst
  for(int e = g; e < N_EDGES; e += COOP_THR) atomicAdd(&cnt[e_dst[e]], 1);
  grid.sync();

  // phase 2: per-tile partial sums (blocks 0..SCAN_NB-1)
  if(bid < SCAN_NB){
    int i0 = bid*SCAN_TILE + tid*8;
    int s = 0;
    #pragma unroll
    for(int j = 0; j < 8; ++j){ int i = i0 + j; s += (i < N_NODES) ? cnt[i] : 0; }
    for(int m = 32; m; m >>= 1) s += __shfl_xor(s, m);
    if((tid & 63) == 0) ws[tid >> 6] = s;
    __syncthreads();
    if(tid == 0) bsum[bid] = ws[0] + ws[1] + ws[2] + ws[3];
  }
  grid.sync();

  // phase 3: tile-local scan + raw-bsum prefix -> offs; zero cnt for cursor reuse
  if(bid < SCAN_NB){
    int lane = tid & 63, wv = tid >> 6;
    int i0 = bid*SCAN_TILE + tid*8;
    int v[8]; int s = 0;
    #pragma unroll
    for(int j = 0; j < 8; ++j){
      int i = i0 + j;
      v[j] = (i < N_NODES) ? cnt[i] : 0;
      s += v[j];
    }
    #pragma unroll
    for(int j = 0; j < 8; ++j){ int i = i0 + j; if(i < N_NODES) cnt[i] = 0; }
    int incl = s;
    for(int sh = 1; sh < 64; sh <<= 1){
      int t = __shfl_up(incl, sh);
      if(lane >= sh) incl += t;
    }
    __shared__ int wtot[4];
    if(lane == 63) wtot[wv] = incl;
    __syncthreads();
    int woff = 0;
    for(int w = 0; w < wv; ++w) woff += wtot[w];
    int excl = woff + incl - s;
    int pre = 0;
    for(int w = 0; w < bid; ++w) pre += bsum[w];
    int run = pre + excl;
    #pragma unroll
    for(int j = 0; j < 8; ++j){
      int i = i0 + j;
      run += v[j];
      if(i < N_NODES) offs[i+1] = run;
    }
    if(bid == 0 && tid == 0) offs[0] = 0;
  }
  grid.sync();

  // phase 4: scatter src into CSR
  for(int e = g; e < N_EDGES; e += COOP_THR){
    int d = e_dst[e];
    int p = offs[d] + atomicAdd(&cnt[d], 1);
    if(p >= 0 && p < N_EDGES) csr[p] = e_src[e];
  }
  grid.sync();

  // phase 5: mark (per-wave nid units)  ||  weight transpose  ||  node_feat cvt
  {
    int gwave = g >> 6, lane = tid & 63;
    for(int u = gwave; u < BB*LL; u += COOP_NB*4){
      unsigned n = (unsigned)nid[u];
      if(n >= N_NODES) continue;
      if(lane == 0) mark[n] = 1;
      int o0 = offs[n], o1 = offs[n+1];
      for(int j = o0 + lane; j < o1; j += 64){
        unsigned s = (unsigned)csr[j];
        if(s < N_NODES) mark[s] = 1;
      }
    }
    for(int i = g; i < HEADS*HDIM*HDIM; i += COOP_THR){
      int n = i >> 7, k = i & 127;
      wt1[i] = __float2bfloat16(W1[k*(HEADS*HDIM) + n]);
      wt2[i] = __float2bfloat16(W2[k*(HEADS*HDIM) + n]);
    }
    for(int u = g; u*8 < N_NODES*HDIM; u += COOP_THR){
      int i = u*8;
      f32x4 lo = *reinterpret_cast<const f32x4*>(nf + i);
      f32x4 hi = *reinterpret_cast<const f32x4*>(nf + i + 4);
      v8bf v;
      #pragma unroll
      for(int j = 0; j < 4; ++j){ v[j] = (__bf16)lo[j]; v[4+j] = (__bf16)hi[j]; }
      *reinterpret_cast<v8bf*>(nfb + i) = v;
    }
  }
  grid.sync();

  // phase 6: compact marked list
  for(int i = g; i < N_NODES; i += COOP_THR){
    if(mark[i]){
      int p = atomicAdd(mcnt, 1);
      mlist[p] = i;
    }
  }
}

// ---------------- GEMM + fused el/er + fp8 feat write ----------------

template<int LIST>
__global__ __launch_bounds__(256) void k_gemm(const bf16* __restrict__ A,
                                              const bf16* __restrict__ Wt,
                                              const float* __restrict__ al,
                                              const float* __restrict__ ar,
                                              fp8t* __restrict__ feat8,
                                              float* __restrict__ el4,
                                              float* __restrict__ er4,
                                              const int* __restrict__ list,
                                              const int* __restrict__ pcnt,
                                              int M){
  int Meff = LIST ? pcnt[0] : M;
  if(blockIdx.x*64 >= Meff) return;
  int tid  = threadIdx.x;
  int wave = tid >> 6, lane = tid & 63;
  int wr = wave >> 1, wc = wave & 1;
  int row0 = blockIdx.x*64 + wr*32;
  int head = blockIdx.y;
  int col0 = head*128 + wc*64;
  int l15 = lane & 15, lhi = lane >> 4;

  v8bf a[4][2], b[4][4];
  int nodeA[2];
  #pragma unroll
  for(int mi = 0; mi < 2; ++mi){
    int r = row0 + mi*16 + l15;
    if(r >= Meff) r = Meff - 1;
    nodeA[mi] = LIST ? list[r] : r;
  }
  #pragma unroll
  for(int kk = 0; kk < 4; ++kk){
    int kb = kk*32 + lhi*8;
    #pragma unroll
    for(int mi = 0; mi < 2; ++mi)
      a[kk][mi] = *reinterpret_cast<const v8bf*>(A + (size_t)nodeA[mi]*HDIM + kb);
    #pragma unroll
    for(int ni = 0; ni < 4; ++ni){
      int c = col0 + ni*16 + l15;
      b[kk][ni] = *reinterpret_cast<const v8bf*>(Wt + (size_t)c*HDIM + kb);
    }
  }

  f32x4 acc[2][4] = {};
  #pragma unroll
  for(int kk = 0; kk < 4; ++kk)
    #pragma unroll
    for(int mi = 0; mi < 2; ++mi)
      #pragma unroll
      for(int ni = 0; ni < 4; ++ni)
        acc[mi][ni] = __builtin_amdgcn_mfma_f32_16x16x32_bf16(a[kk][mi], b[kk][ni],
                                                              acc[mi][ni], 0, 0, 0);

  const float* alh = al + head*HDIM;
  const float* arh = ar + head*HDIM;
  float alv[4], arv[4];
  #pragma unroll
  for(int ni = 0; ni < 4; ++ni){
    int d = wc*64 + ni*16 + l15;
    alv[ni] = alh[d]; arv[ni] = arh[d];
  }
  __shared__ float red[2][64][2];
  __shared__ int4 tile4[512];
  fp8t* tile8 = (fp8t*)tile4;

  #pragma unroll
  for(int mi = 0; mi < 2; ++mi){
    #pragma unroll
    for(int j = 0; j < 4; ++j){
      float pe = 0.f, pr = 0.f;
      #pragma unroll
      for(int ni = 0; ni < 4; ++ni){
        pe += acc[mi][ni][j]*alv[ni];
        pr += acc[mi][ni][j]*arv[ni];
      }
      for(int k = 8; k; k >>= 1){ pe += __shfl_xor(pe, k); pr += __shfl_xor(pr, k); }
      int row_l = wr*32 + mi*16 + lhi*4 + j;
      if(l15 == 0){ red[wc][row_l][0] = pe; red[wc][row_l][1] = pr; }
    }
  }
  #pragma unroll
  for(int mi = 0; mi < 2; ++mi)
    #pragma unroll
    for(int j = 0; j < 4; ++j){
      int row_l = wr*32 + mi*16 + lhi*4 + j;
      #pragma unroll
      for(int ni = 0; ni < 4; ++ni){
        float x = acc[mi][ni][j];
        unsigned bb = (unsigned)__builtin_amdgcn_cvt_pk_fp8_f32(x, x, 0, false) & 0xFFu;
        tile8[row_l*128 + wc*64 + ni*16 + l15] = (fp8t)bb;
      }
    }
  __syncthreads();

  if(tid < 64){
    int r = blockIdx.x*64 + tid;
    if(r < Meff){
      int node = LIST ? list[r] : r;
      el4[(size_t)node*4 + head] = red[0][tid][0] + red[1][tid][0];
      er4[(size_t)node*4 + head] = red[0][tid][1] + red[1][tid][1];
    }
  }
  #pragma unroll
  for(int pass = 0; pass < 2; ++pass){
    int off = pass*4096 + tid*16;
    int row_l = off >> 7, col = off & 127;
    int r = blockIdx.x*64 + row_l;
    if(r < Meff){
      int node = LIST ? list[r] : r;
      *reinterpret_cast<int4*>(feat8 + (size_t)node*(HEADS*HDIM) + head*HDIM + col) =
          tile4[off >> 4];
    }
  }
}

// ---------------- aggregation: one WAVE per node, redundant alpha -----------

__device__ __forceinline__ float lrelu(float x){ return x > 0.f ? x : NEG_SLOPE*x; }
template<int SEL>
__device__ __forceinline__ float cv8(unsigned u){
  return __builtin_amdgcn_cvt_f32_fp8((int)u, SEL);
}

#define SEQ_SZ   (BB*LL*4*HDIM)
#define SEQR_OFF SEQ_SZ
#define SEQR_SZ  (BB*LL*3*HDIM)
#define SH_OFF   (SEQ_SZ + SEQR_SZ)

template<int USE_LIST, int FUSED, int USE_PCNT>
__global__ __launch_bounds__(64) void k_agg(const fp8t* __restrict__ feat8,
                                            const float* __restrict__ el4,
                                            const float* __restrict__ er4,
                                            const float* __restrict__ bias,
                                            const int* __restrict__ offs,
                                            const int* __restrict__ csr,
                                            const int* __restrict__ list,
                                            const int* __restrict__ pcnt,
                                            bf16* __restrict__ h1,
                                            const float* __restrict__ ent_e,
                                            const float* __restrict__ rel_e,
                                            const float* __restrict__ glob,
                                            const float* __restrict__ sht,
                                            const int* __restrict__ s_tem,
                                            const int* __restrict__ r_tem,
                                            float* __restrict__ out,
                                            int total){
  int widx = blockIdx.x;
  int lane = threadIdx.x;
  int bound = USE_PCNT ? pcnt[0] : total;
  if(widx >= bound) return;
  int n = USE_LIST ? list[widx] : widx;
  int o0 = offs[n];
  int deg = offs[n+1] - o0;
  if(deg < 0 || deg > N_EDGES) deg = 0;
  float4 erv = *reinterpret_cast<const float4*>(er4 + (size_t)n*4);
  int hA = lane >> 5;
  float erA = hA ? erv.y : erv.x;
  float er2 = erv.z;
  bool lo = lane < 32;

  float a0=0.f,a1=0.f,a2=0.f,a3=0.f,dhA=0.f;
  float b0=0.f,b1=0.f,b2=0.f,b3=0.f,dh2=0.f;

  int e = 0;
  for(; e + 4 <= deg; e += 4){
    unsigned s0,s1,s2,s3;
    { unsigned t=(unsigned)csr[o0+e+0]; s0 = (t<N_NODES)?t:0; }
    { unsigned t=(unsigned)csr[o0+e+1]; s1 = (t<N_NODES)?t:0; }
    { unsigned t=(unsigned)csr[o0+e+2]; s2 = (t<N_NODES)?t:0; }
    { unsigned t=(unsigned)csr[o0+e+3]; s3 = (t<N_NODES)?t:0; }
    float4 v0 = *reinterpret_cast<const float4*>(el4 + (size_t)s0*4);
    float4 v1 = *reinterpret_cast<const float4*>(el4 + (size_t)s1*4);
    float4 v2 = *reinterpret_cast<const float4*>(el4 + (size_t)s2*4);
    float4 v3 = *reinterpret_cast<const float4*>(el4 + (size_t)s3*4);
    const fp8t* f0 = feat8 + (size_t)s0*(HEADS*HDIM);
    const fp8t* f1 = feat8 + (size_t)s1*(HEADS*HDIM);
    const fp8t* f2 = feat8 + (size_t)s2*(HEADS*HDIM);
    const fp8t* f3 = feat8 + (size_t)s3*(HEADS*HDIM);
    unsigned uA0 = *reinterpret_cast<const unsigned*>(f0 + lane*4);
    unsigned uA1 = *reinterpret_cast<const unsigned*>(f1 + lane*4);
    unsigned uA2 = *reinterpret_cast<const unsigned*>(f2 + lane*4);
    unsigned uA3 = *reinterpret_cast<const unsigned*>(f3 + lane*4);
    unsigned uB0=0,uB1=0,uB2=0,uB3=0;
    if(lo){
      uB0 = *reinterpret_cast<const unsigned*>(f0 + 256 + lane*4);
      uB1 = *reinterpret_cast<const unsigned*>(f1 + 256 + lane*4);
      uB2 = *reinterpret_cast<const unsigned*>(f2 + 256 + lane*4);
      uB3 = *reinterpret_cast<const unsigned*>(f3 + 256 + lane*4);
    }
    float alA0 = __expf(lrelu((hA ? v0.y : v0.x) + erA));
    float alA1 = __expf(lrelu((hA ? v1.y : v1.x) + erA));
    float alA2 = __expf(lrelu((hA ? v2.y : v2.x) + erA));
    float alA3 = __expf(lrelu((hA ? v3.y : v3.x) + erA));
    dhA += alA0 + alA1 + alA2 + alA3;
    a0 += alA0*cv8<0>(uA0) + alA1*cv8<0>(uA1) + alA2*cv8<0>(uA2) + alA3*cv8<0>(uA3);
    a1 += alA0*cv8<1>(uA0) + alA1*cv8<1>(uA1) + alA2*cv8<1>(uA2) + alA3*cv8<1>(uA3);
    a2 += alA0*cv8<2>(uA0) + alA1*cv8<2>(uA1) + alA2*cv8<2>(uA2) + alA3*cv8<2>(uA3);
    a3 += alA0*cv8<3>(uA0) + alA1*cv8<3>(uA1) + alA2*cv8<3>(uA2) + alA3*cv8<3>(uA3);
    if(lo){
      float al20 = __expf(lrelu(v0.z + er2));
      float al21 = __expf(lrelu(v1.z + er2));
      float al22 = __expf(lrelu(v2.z + er2));
      float al23 = __expf(lrelu(v3.z + er2));
      dh2 += al20 + al21 + al22 + al23;
      b0 += al20*cv8<0>(uB0) + al21*cv8<0>(uB1) + al22*cv8<0>(uB2) + al23*cv8<0>(uB3);
      b1 += al20*cv8<1>(uB0) + al21*cv8<1>(uB1) + al22*cv8<1>(uB2) + al23*cv8<1>(uB3);
      b2 += al20*cv8<2>(uB0) + al21*cv8<2>(uB1) + al22*cv8<2>(uB2) + al23*cv8<2>(uB3);
      b3 += al20*cv8<3>(uB0) + al21*cv8<3>(uB1) + al22*cv8<3>(uB2) + al23*cv8<3>(uB3);
    }
  }
  for(; e < deg; ++e){
    unsigned t = (unsigned)csr[o0+e];
    unsigned s = (t < N_NODES) ? t : 0;
    float4 v = *reinterpret_cast<const float4*>(el4 + (size_t)s*4);
    const fp8t* fr = feat8 + (size_t)s*(HEADS*HDIM);
    unsigned uA = *reinterpret_cast<const unsigned*>(fr + lane*4);
    float alA = __expf(lrelu((hA ? v.y : v.x) + erA));
    dhA += alA;
    a0 += alA*cv8<0>(uA); a1 += alA*cv8<1>(uA);
    a2 += alA*cv8<2>(uA); a3 += alA*cv8<3>(uA);
    if(lo){
      unsigned uB = *reinterpret_cast<const unsigned*>(fr + 256 + lane*4);
      float al2 = __expf(lrelu(v.z + er2));
      dh2 += al2;
      b0 += al2*cv8<0>(uB); b1 += al2*cv8<1>(uB);
      b2 += al2*cv8<2>(uB); b3 += al2*cv8<3>(uB);
    }
  }

  float invA = (dhA > 0.f) ? 1.f/dhA : 0.f;
  float inv2 = (dh2 > 0.f) ? 1.f/dh2 : 0.f;
  float nA0 = a0*invA, nA1 = a1*invA, nA2 = a2*invA, nA3 = a3*invA;
  float x0 = __shfl(nA0, lane + 32);
  float x1 = __shfl(nA1, lane + 32);
  float x2 = __shfl(nA2, lane + 32);
  float x3 = __shfl(nA3, lane + 32);
  if(lo){
    int m = lane;
    float4 bs0 = *reinterpret_cast<const float4*>(bias + 4*m);
    float4 bs1 = *reinterpret_cast<const float4*>(bias + HDIM + 4*m);
    float4 bs2 = *reinterpret_cast<const float4*>(bias + 2*HDIM + 4*m);
    float4 r;
    r.x = (nA0 + x0 + b0*inv2 + bs0.x + bs1.x + bs2.x)*(1.f/3.f);
    r.y = (nA1 + x1 + b1*inv2 + bs0.y + bs1.y + bs2.y)*(1.f/3.f);
    r.z = (nA2 + x2 + b2*inv2 + bs0.z + bs1.z + bs2.z)*(1.f/3.f);
    r.w = (nA3 + x3 + b3*inv2 + bs0.w + bs1.w + bs2.w)*(1.f/3.f);
    if(FUSED){
      int p = widx, bb = p/LL;
      float4 ent = *reinterpret_cast<const float4*>(ent_e + (size_t)s_tem[bb]*HDIM + 4*m);
      float4 rel = *reinterpret_cast<const float4*>(rel_e + (size_t)r_tem[bb]*HDIM + 4*m);
      float4 gl  = *reinterpret_cast<const float4*>(glob + (size_t)p*HDIM + 4*m);
      float* so = out + (size_t)p*(4*HDIM) + 4*m;
      *reinterpret_cast<float4*>(so)          = r;
      *reinterpret_cast<float4*>(so + HDIM)   = ent;
      *reinterpret_cast<float4*>(so + 2*HDIM) = rel;
      *reinterpret_cast<float4*>(so + 3*HDIM) = gl;
      float* ro = out + SEQR_OFF + (size_t)p*(3*HDIM) + 4*m;
      *reinterpret_cast<float4*>(ro)          = r;
      *reinterpret_cast<float4*>(ro + HDIM)   = ent;
      *reinterpret_cast<float4*>(ro + 2*HDIM) = gl;
      if(m == 0) out[SH_OFF + p] = sht[p];
    } else {
      bf16 t0 = __float2bfloat16(r.x), t1 = __float2bfloat16(r.y);
      bf16 t2 = __float2bfloat16(r.z), t3 = __float2bfloat16(r.w);
      ushort4 hv;
      hv.x = *reinterpret_cast<unsigned short*>(&t0);
      hv.y = *reinterpret_cast<unsigned short*>(&t1);
      hv.z = *reinterpret_cast<unsigned short*>(&t2);
      hv.w = *reinterpret_cast<unsigned short*>(&t3);
      *reinterpret_cast<ushort4*>(h1 + (size_t)n*HDIM + 4*m) = hv;
    }
  }
}

// ---------------- launch ----------------

extern "C" void kernel_launch(void* const* d_in, const int* in_sizes, int n_in,
                              void* d_out, int out_size, void* d_ws, size_t ws_size,
                              hipStream_t stream){
  const float* node_feat = (const float*)d_in[0];
  const float* W1        = (const float*)d_in[1];
  const float* attn_l1   = (const float*)d_in[2];
  const float* attn_r1   = (const float*)d_in[3];
  const float* b1        = (const float*)d_in[4];
  const float* W2        = (const float*)d_in[5];
  const float* attn_l2   = (const float*)d_in[6];
  const float* attn_r2   = (const float*)d_in[7];
  const float* b2        = (const float*)d_in[8];
  const float* ent_emb   = (const float*)d_in[9];
  const float* rel_emb   = (const float*)d_in[10];
  const float* glob      = (const float*)d_in[11];
  const float* sht       = (const float*)d_in[12];
  const int*  e_src      = (const int*)d_in[13];
  const int*  e_dst      = (const int*)d_in[14];
  const int*  nid        = (const int*)d_in[15];
  const int*  s_tem      = (const int*)d_in[16];
  const int*  r_tem      = (const int*)d_in[17];
  float* out = (float*)d_out;

  char* ws = (char*)d_ws;
  size_t cur_off = 0;
  auto alloc = [&](size_t bytes)->char*{
    char* r = ws + cur_off;
    cur_off += (bytes + 255) & ~(size_t)255;
    return r;
  };
  fp8t*  feat8 = (fp8t*) alloc((size_t)N_NODES*HEADS*HDIM);
  bf16*  nfb   = (bf16*) alloc((size_t)N_NODES*HDIM*2);
  bf16*  h1    = (bf16*) alloc((size_t)N_NODES*HDIM*2);
  float* el4   = (float*)alloc((size_t)N_NODES*4*4);
  float* er4   = (float*)alloc((size_t)N_NODES*4*4);
  bf16*  wt1   = (bf16*) alloc((size_t)HEADS*HDIM*HDIM*2);
  bf16*  wt2   = (bf16*) alloc((size_t)HEADS*HDIM*HDIM*2);
  int*   offs  = (int*)  alloc((size_t)(N_NODES+1)*4);
  int*   cnt   = (int*)  alloc((size_t)N_NODES*4);
  int*   bsum  = (int*)  alloc((size_t)SCAN_NB*4);
  unsigned char* mark = (unsigned char*)alloc((size_t)N_NODES);
  int*   mlist = (int*)  alloc((size_t)N_NODES*4);
  int*   mcnt  = (int*)  alloc(256);
  int*   csr   = (int*)  alloc((size_t)N_EDGES*4);

  // --- single cooperative prologue ---
  {
    void* args[] = { (void*)&e_src, (void*)&e_dst, (void*)&nid,
                     (void*)&cnt, (void*)&bsum, (void*)&offs, (void*)&csr,
                     (void*)&mark, (void*)&mlist, (void*)&mcnt,
                     (void*)&W1, (void*)&W2, (void*)&wt1, (void*)&wt2,
                     (void*)&node_feat, (void*)&nfb };
    hipLaunchCooperativeKernel((const void*)k_csr, dim3(COOP_NB), dim3(256),
                               args, 0, stream);
  }

  dim3 ggrid((N_NODES + 63)/64, HEADS);

  // Layer 1 (agg over marked list only)
  k_gemm<0><<<ggrid, 256, 0, stream>>>(nfb, wt1, attn_l1, attn_r1,
                                       feat8, el4, er4, nullptr, nullptr, N_NODES);
  k_agg<1,0,1><<<N_NODES, 64, 0, stream>>>(feat8, el4, er4, b1, offs, csr,
                                           mlist, mcnt, h1,
                                           nullptr, nullptr, nullptr, nullptr,
                                           nullptr, nullptr, nullptr, N_NODES);

  // Layer 2 (gemm over marked rows; agg fused with assembly)
  k_gemm<1><<<ggrid, 256, 0, stream>>>(h1, wt2, attn_l2, attn_r2,
                                       feat8, el4, er4, mlist, mcnt, N_NODES);
  k_agg<1,1,0><<<BB*LL, 64, 0, stream>>>(feat8, el4, er4, b2, offs, csr,
                                         nid, nullptr, nullptr,
                                         ent_emb, rel_emb, glob, sht,
                                         s_tem, r_tem, out, BB*LL);
}

// Round 17
// 185.332 us; speedup vs baseline: 4.2377x; 4.2377x over previous
//
#include <hip/hip_runtime.h>
#include <hip/hip_bf16.h>

#define N_NODES 50000
#define N_EDGES 500000
#define HDIM 128
#define HEADS 3
#define BB 512
#define LL 10
#define NEG_SLOPE 0.2f

typedef __hip_bfloat16 bf16;
typedef unsigned char fp8t;
typedef __bf16 v8bf __attribute__((ext_vector_type(8)));
typedef float f32x4 __attribute__((ext_vector_type(4)));

// ---------------- init: zero cnt + mark + mcnt ----------------

__global__ void k_init(int* cnt, int* markw, int* mcnt){
  int i = blockIdx.x*256 + threadIdx.x;
  if(i < N_NODES) cnt[i] = 0;
  if(i < (N_NODES+3)/4) markw[i] = 0;
  if(i == 0) mcnt[0] = 0;
}

// ---------------- fused: hist + W transposes + node_feat cvt ----------------

#define HIST_NB ((N_EDGES + 255)/256)            // 1954
#define WT_NB   ((HEADS*HDIM*HDIM + 255)/256)    // 384
#define CVT_NB  ((N_NODES*HDIM/8 + 255)/256)     // 3125
#define MISC_NB (HIST_NB + WT_NB + CVT_NB)

__global__ __launch_bounds__(256) void k_misc(const int* __restrict__ e_dst,
                                              int* __restrict__ cnt,
                                              const float* __restrict__ W1,
                                              const float* __restrict__ W2,
                                              bf16* __restrict__ wt1,
                                              bf16* __restrict__ wt2,
                                              const float* __restrict__ nf,
                                              bf16* __restrict__ nfb){
  int b = blockIdx.x;
  if(b < HIST_NB){
    int e = b*256 + threadIdx.x;
    if(e < N_EDGES) atomicAdd(&cnt[e_dst[e]], 1);
  } else if(b < HIST_NB + WT_NB){
    int i = (b - HIST_NB)*256 + threadIdx.x;
    if(i < HEADS*HDIM*HDIM){
      int n = i >> 7, k = i & 127;
      wt1[i] = __float2bfloat16(W1[k*(HEADS*HDIM) + n]);
      wt2[i] = __float2bfloat16(W2[k*(HEADS*HDIM) + n]);
    }
  } else {
    int i = ((b - HIST_NB - WT_NB)*256 + threadIdx.x)*8;
    if(i < N_NODES*HDIM){
      f32x4 lo = *reinterpret_cast<const f32x4*>(nf + i);
      f32x4 hi = *reinterpret_cast<const f32x4*>(nf + i + 4);
      v8bf v;
      #pragma unroll
      for(int j = 0; j < 4; ++j){ v[j] = (__bf16)lo[j]; v[4+j] = (__bf16)hi[j]; }
      *reinterpret_cast<v8bf*>(nfb + i) = v;
    }
  }
}

// ---------------- hierarchical scan (top level inlined in write) ------------

#define SCAN_TILE 2048
#define SCAN_NB ((N_NODES + SCAN_TILE - 1)/SCAN_TILE)   // 25

__global__ __launch_bounds__(256) void k_scan_part(const int* __restrict__ cnt,
                                                   int* __restrict__ bsum){
  int b = blockIdx.x, tid = threadIdx.x;
  int i0 = b*SCAN_TILE + tid*8;
  int s = 0;
  #pragma unroll
  for(int j = 0; j < 8; ++j){ int i = i0 + j; s += (i < N_NODES) ? cnt[i] : 0; }
  for(int m = 32; m; m >>= 1) s += __shfl_xor(s, m);
  __shared__ int ws[4];
  if((tid & 63) == 0) ws[tid >> 6] = s;
  __syncthreads();
  if(tid == 0) bsum[b] = ws[0] + ws[1] + ws[2] + ws[3];
}

__global__ __launch_bounds__(256) void k_scan_write(int* __restrict__ cnt,
                                                    const int* __restrict__ bsum,
                                                    int* __restrict__ offs){
  int b = blockIdx.x, tid = threadIdx.x;
  int lane = tid & 63, wv = tid >> 6;
  int i0 = b*SCAN_TILE + tid*8;
  int v[8]; int s = 0;
  #pragma unroll
  for(int j = 0; j < 8; ++j){
    int i = i0 + j;
    v[j] = (i < N_NODES) ? cnt[i] : 0;
    s += v[j];
  }
  #pragma unroll
  for(int j = 0; j < 8; ++j){ int i = i0 + j; if(i < N_NODES) cnt[i] = 0; }
  int incl = s;
  for(int sh = 1; sh < 64; sh <<= 1){
    int t = __shfl_up(incl, sh);
    if(lane >= sh) incl += t;
  }
  __shared__ int wtot[4];
  if(lane == 63) wtot[wv] = incl;
  __syncthreads();
  int woff = 0;
  for(int w = 0; w < wv; ++w) woff += wtot[w];
  int excl = woff + incl - s;
  int pre = 0;                                   // inline top-level scan (raw bsum)
  for(int w = 0; w < b; ++w) pre += bsum[w];
  int run = pre + excl;
  #pragma unroll
  for(int j = 0; j < 8; ++j){
    int i = i0 + j;
    run += v[j];
    if(i < N_NODES) offs[i+1] = run;
  }
  if(b == 0 && tid == 0) offs[0] = 0;
}

__global__ void k_scatter(const int* __restrict__ src, const int* __restrict__ dst,
                          const int* __restrict__ offs, int* __restrict__ cur,
                          int* __restrict__ csr, int E){
  int e = blockIdx.x*256 + threadIdx.x;
  if(e < E){
    int d = dst[e];
    int p = offs[d] + atomicAdd(&cur[d], 1);
    if(p >= 0 && p < E) csr[p] = src[e];
  }
}

// ---------------- mark (plain stores) + compact list (separate) -------------

__global__ __launch_bounds__(64) void k_mark(const int* __restrict__ nid,
                                             const int* __restrict__ offs,
                                             const int* __restrict__ csr,
                                             unsigned char* __restrict__ mark){
  unsigned n = (unsigned)nid[blockIdx.x];
  if(n >= N_NODES) return;
  if(threadIdx.x == 0) mark[n] = 1;
  int o0 = offs[n], o1 = offs[n+1];
  for(int j = o0 + (int)threadIdx.x; j < o1; j += 64){
    unsigned s = (unsigned)csr[j];
    if(s < N_NODES) mark[s] = 1;
  }
}

__global__ void k_mklist(const unsigned char* __restrict__ mark,
                         int* __restrict__ list, int* __restrict__ cnt){
  int i = blockIdx.x*256 + threadIdx.x;
  if(i < N_NODES && mark[i]){
    int p = atomicAdd(cnt, 1);
    list[p] = i;
  }
}

// ---------------- GEMM + fused el/er + fp8 feat write ----------------

template<int LIST>
__global__ __launch_bounds__(256) void k_gemm(const bf16* __restrict__ A,
                                              const bf16* __restrict__ Wt,
                                              const float* __restrict__ al,
                                              const float* __restrict__ ar,
                                              fp8t* __restrict__ feat8,
                                              float* __restrict__ el4,
                                              float* __restrict__ er4,
                                              const int* __restrict__ list,
                                              const int* __restrict__ pcnt,
                                              int M){
  int Meff = LIST ? pcnt[0] : M;
  if(blockIdx.x*64 >= Meff) return;
  int tid  = threadIdx.x;
  int wave = tid >> 6, lane = tid & 63;
  int wr = wave >> 1, wc = wave & 1;
  int row0 = blockIdx.x*64 + wr*32;
  int head = blockIdx.y;
  int col0 = head*128 + wc*64;
  int l15 = lane & 15, lhi = lane >> 4;

  v8bf a[4][2], b[4][4];
  int nodeA[2];
  #pragma unroll
  for(int mi = 0; mi < 2; ++mi){
    int r = row0 + mi*16 + l15;
    if(r >= Meff) r = Meff - 1;
    nodeA[mi] = LIST ? list[r] : r;
  }
  #pragma unroll
  for(int kk = 0; kk < 4; ++kk){
    int kb = kk*32 + lhi*8;
    #pragma unroll
    for(int mi = 0; mi < 2; ++mi)
      a[kk][mi] = *reinterpret_cast<const v8bf*>(A + (size_t)nodeA[mi]*HDIM + kb);
    #pragma unroll
    for(int ni = 0; ni < 4; ++ni){
      int c = col0 + ni*16 + l15;
      b[kk][ni] = *reinterpret_cast<const v8bf*>(Wt + (size_t)c*HDIM + kb);
    }
  }

  f32x4 acc[2][4] = {};
  #pragma unroll
  for(int kk = 0; kk < 4; ++kk)
    #pragma unroll
    for(int mi = 0; mi < 2; ++mi)
      #pragma unroll
      for(int ni = 0; ni < 4; ++ni)
        acc[mi][ni] = __builtin_amdgcn_mfma_f32_16x16x32_bf16(a[kk][mi], b[kk][ni],
                                                              acc[mi][ni], 0, 0, 0);

  const float* alh = al + head*HDIM;
  const float* arh = ar + head*HDIM;
  float alv[4], arv[4];
  #pragma unroll
  for(int ni = 0; ni < 4; ++ni){
    int d = wc*64 + ni*16 + l15;
    alv[ni] = alh[d]; arv[ni] = arh[d];
  }
  __shared__ float red[2][64][2];
  __shared__ int4 tile4[512];
  fp8t* tile8 = (fp8t*)tile4;

  #pragma unroll
  for(int mi = 0; mi < 2; ++mi){
    #pragma unroll
    for(int j = 0; j < 4; ++j){
      float pe = 0.f, pr = 0.f;
      #pragma unroll
      for(int ni = 0; ni < 4; ++ni){
        pe += acc[mi][ni][j]*alv[ni];
        pr += acc[mi][ni][j]*arv[ni];
      }
      for(int k = 8; k; k >>= 1){ pe += __shfl_xor(pe, k); pr += __shfl_xor(pr, k); }
      int row_l = wr*32 + mi*16 + lhi*4 + j;
      if(l15 == 0){ red[wc][row_l][0] = pe; red[wc][row_l][1] = pr; }
    }
  }
  #pragma unroll
  for(int mi = 0; mi < 2; ++mi)
    #pragma unroll
    for(int j = 0; j < 4; ++j){
      int row_l = wr*32 + mi*16 + lhi*4 + j;
      #pragma unroll
      for(int ni = 0; ni < 4; ++ni){
        float x = acc[mi][ni][j];
        unsigned bb = (unsigned)__builtin_amdgcn_cvt_pk_fp8_f32(x, x, 0, false) & 0xFFu;
        tile8[row_l*128 + wc*64 + ni*16 + l15] = (fp8t)bb;
      }
    }
  __syncthreads();

  if(tid < 64){
    int r = blockIdx.x*64 + tid;
    if(r < Meff){
      int node = LIST ? list[r] : r;
      el4[(size_t)node*4 + head] = red[0][tid][0] + red[1][tid][0];
      er4[(size_t)node*4 + head] = red[0][tid][1] + red[1][tid][1];
    }
  }
  #pragma unroll
  for(int pass = 0; pass < 2; ++pass){
    int off = pass*4096 + tid*16;
    int row_l = off >> 7, col = off & 127;
    int r = blockIdx.x*64 + row_l;
    if(r < Meff){
      int node = LIST ? list[r] : r;
      *reinterpret_cast<int4*>(feat8 + (size_t)node*(HEADS*HDIM) + head*HDIM + col) =
          tile4[off >> 4];
    }
  }
}

// ---------------- aggregation: one WAVE per node, redundant alpha -----------

__device__ __forceinline__ float lrelu(float x){ return x > 0.f ? x : NEG_SLOPE*x; }
template<int SEL>
__device__ __forceinline__ float cv8(unsigned u){
  return __builtin_amdgcn_cvt_f32_fp8((int)u, SEL);
}

#define SEQ_SZ   (BB*LL*4*HDIM)
#define SEQR_OFF SEQ_SZ
#define SEQR_SZ  (BB*LL*3*HDIM)
#define SH_OFF   (SEQ_SZ + SEQR_SZ)

template<int USE_LIST, int FUSED, int USE_PCNT>
__global__ __launch_bounds__(64) void k_agg(const fp8t* __restrict__ feat8,
                                            const float* __restrict__ el4,
                                            const float* __restrict__ er4,
                                            const float* __restrict__ bias,
                                            const int* __restrict__ offs,
                                            const int* __restrict__ csr,
                                            const int* __restrict__ list,
                                            const int* __restrict__ pcnt,
                                            bf16* __restrict__ h1,
                                            const float* __restrict__ ent_e,
                                            const float* __restrict__ rel_e,
                                            const float* __restrict__ glob,
                                            const float* __restrict__ sht,
                                            const int* __restrict__ s_tem,
                                            const int* __restrict__ r_tem,
                                            float* __restrict__ out,
                                            int total){
  int widx = blockIdx.x;
  int lane = threadIdx.x;
  int bound = USE_PCNT ? pcnt[0] : total;
  if(widx >= bound) return;
  int n = USE_LIST ? list[widx] : widx;
  int o0 = offs[n];
  int deg = offs[n+1] - o0;
  if(deg < 0 || deg > N_EDGES) deg = 0;
  float4 erv = *reinterpret_cast<const float4*>(er4 + (size_t)n*4);
  int hA = lane >> 5;
  float erA = hA ? erv.y : erv.x;
  float er2 = erv.z;
  bool lo = lane < 32;

  float a0=0.f,a1=0.f,a2=0.f,a3=0.f,dhA=0.f;
  float b0=0.f,b1=0.f,b2=0.f,b3=0.f,dh2=0.f;

  int e = 0;
  for(; e + 4 <= deg; e += 4){
    unsigned s0,s1,s2,s3;
    { unsigned t=(unsigned)csr[o0+e+0]; s0 = (t<N_NODES)?t:0; }
    { unsigned t=(unsigned)csr[o0+e+1]; s1 = (t<N_NODES)?t:0; }
    { unsigned t=(unsigned)csr[o0+e+2]; s2 = (t<N_NODES)?t:0; }
    { unsigned t=(unsigned)csr[o0+e+3]; s3 = (t<N_NODES)?t:0; }
    float4 v0 = *reinterpret_cast<const float4*>(el4 + (size_t)s0*4);
    float4 v1 = *reinterpret_cast<const float4*>(el4 + (size_t)s1*4);
    float4 v2 = *reinterpret_cast<const float4*>(el4 + (size_t)s2*4);
    float4 v3 = *reinterpret_cast<const float4*>(el4 + (size_t)s3*4);
    const fp8t* f0 = feat8 + (size_t)s0*(HEADS*HDIM);
    const fp8t* f1 = feat8 + (size_t)s1*(HEADS*HDIM);
    const fp8t* f2 = feat8 + (size_t)s2*(HEADS*HDIM);
    const fp8t* f3 = feat8 + (size_t)s3*(HEADS*HDIM);
    unsigned uA0 = *reinterpret_cast<const unsigned*>(f0 + lane*4);
    unsigned uA1 = *reinterpret_cast<const unsigned*>(f1 + lane*4);
    unsigned uA2 = *reinterpret_cast<const unsigned*>(f2 + lane*4);
    unsigned uA3 = *reinterpret_cast<const unsigned*>(f3 + lane*4);
    unsigned uB0=0,uB1=0,uB2=0,uB3=0;
    if(lo){
      uB0 = *reinterpret_cast<const unsigned*>(f0 + 256 + lane*4);
      uB1 = *reinterpret_cast<const unsigned*>(f1 + 256 + lane*4);
      uB2 = *reinterpret_cast<const unsigned*>(f2 + 256 + lane*4);
      uB3 = *reinterpret_cast<const unsigned*>(f3 + 256 + lane*4);
    }
    float alA0 = __expf(lrelu((hA ? v0.y : v0.x) + erA));
    float alA1 = __expf(lrelu((hA ? v1.y : v1.x) + erA));
    float alA2 = __expf(lrelu((hA ? v2.y : v2.x) + erA));
    float alA3 = __expf(lrelu((hA ? v3.y : v3.x) + erA));
    dhA += alA0 + alA1 + alA2 + alA3;
    a0 += alA0*cv8<0>(uA0) + alA1*cv8<0>(uA1) + alA2*cv8<0>(uA2) + alA3*cv8<0>(uA3);
    a1 += alA0*cv8<1>(uA0) + alA1*cv8<1>(uA1) + alA2*cv8<1>(uA2) + alA3*cv8<1>(uA3);
    a2 += alA0*cv8<2>(uA0) + alA1*cv8<2>(uA1) + alA2*cv8<2>(uA2) + alA3*cv8<2>(uA3);
    a3 += alA0*cv8<3>(uA0) + alA1*cv8<3>(uA1) + alA2*cv8<3>(uA2) + alA3*cv8<3>(uA3);
    if(lo){
      float al20 = __expf(lrelu(v0.z + er2));
      float al21 = __expf(lrelu(v1.z + er2));
      float al22 = __expf(lrelu(v2.z + er2));
      float al23 = __expf(lrelu(v3.z + er2));
      dh2 += al20 + al21 + al22 + al23;
      b0 += al20*cv8<0>(uB0) + al21*cv8<0>(uB1) + al22*cv8<0>(uB2) + al23*cv8<0>(uB3);
      b1 += al20*cv8<1>(uB0) + al21*cv8<1>(uB1) + al22*cv8<1>(uB2) + al23*cv8<1>(uB3);
      b2 += al20*cv8<2>(uB0) + al21*cv8<2>(uB1) + al22*cv8<2>(uB2) + al23*cv8<2>(uB3);
      b3 += al20*cv8<3>(uB0) + al21*cv8<3>(uB1) + al22*cv8<3>(uB2) + al23*cv8<3>(uB3);
    }
  }
  for(; e < deg; ++e){
    unsigned t = (unsigned)csr[o0+e];
    unsigned s = (t < N_NODES) ? t : 0;
    float4 v = *reinterpret_cast<const float4*>(el4 + (size_t)s*4);
    const fp8t* fr = feat8 + (size_t)s*(HEADS*HDIM);
    unsigned uA = *reinterpret_cast<const unsigned*>(fr + lane*4);
    float alA = __expf(lrelu((hA ? v.y : v.x) + erA));
    dhA += alA;
    a0 += alA*cv8<0>(uA); a1 += alA*cv8<1>(uA);
    a2 += alA*cv8<2>(uA); a3 += alA*cv8<3>(uA);
    if(lo){
      unsigned uB = *reinterpret_cast<const unsigned*>(fr + 256 + lane*4);
      float al2 = __expf(lrelu(v.z + er2));
      dh2 += al2;
      b0 += al2*cv8<0>(uB); b1 += al2*cv8<1>(uB);
      b2 += al2*cv8<2>(uB); b3 += al2*cv8<3>(uB);
    }
  }

  float invA = (dhA > 0.f) ? 1.f/dhA : 0.f;
  float inv2 = (dh2 > 0.f) ? 1.f/dh2 : 0.f;
  float nA0 = a0*invA, nA1 = a1*invA, nA2 = a2*invA, nA3 = a3*invA;
  float x0 = __shfl(nA0, lane + 32);
  float x1 = __shfl(nA1, lane + 32);
  float x2 = __shfl(nA2, lane + 32);
  float x3 = __shfl(nA3, lane + 32);
  if(lo){
    int m = lane;
    float4 bs0 = *reinterpret_cast<const float4*>(bias + 4*m);
    float4 bs1 = *reinterpret_cast<const float4*>(bias + HDIM + 4*m);
    float4 bs2 = *reinterpret_cast<const float4*>(bias + 2*HDIM + 4*m);
    float4 r;
    r.x = (nA0 + x0 + b0*inv2 + bs0.x + bs1.x + bs2.x)*(1.f/3.f);
    r.y = (nA1 + x1 + b1*inv2 + bs0.y + bs1.y + bs2.y)*(1.f/3.f);
    r.z = (nA2 + x2 + b2*inv2 + bs0.z + bs1.z + bs2.z)*(1.f/3.f);
    r.w = (nA3 + x3 + b3*inv2 + bs0.w + bs1.w + bs2.w)*(1.f/3.f);
    if(FUSED){
      int p = widx, bb = p/LL;
      float4 ent = *reinterpret_cast<const float4*>(ent_e + (size_t)s_tem[bb]*HDIM + 4*m);
      float4 rel = *reinterpret_cast<const float4*>(rel_e + (size_t)r_tem[bb]*HDIM + 4*m);
      float4 gl  = *reinterpret_cast<const float4*>(glob + (size_t)p*HDIM + 4*m);
      float* so = out + (size_t)p*(4*HDIM) + 4*m;
      *reinterpret_cast<float4*>(so)          = r;
      *reinterpret_cast<float4*>(so + HDIM)   = ent;
      *reinterpret_cast<float4*>(so + 2*HDIM) = rel;
      *reinterpret_cast<float4*>(so + 3*HDIM) = gl;
      float* ro = out + SEQR_OFF + (size_t)p*(3*HDIM) + 4*m;
      *reinterpret_cast<float4*>(ro)          = r;
      *reinterpret_cast<float4*>(ro + HDIM)   = ent;
      *reinterpret_cast<float4*>(ro + 2*HDIM) = gl;
      if(m == 0) out[SH_OFF + p] = sht[p];
    } else {
      bf16 t0 = __float2bfloat16(r.x), t1 = __float2bfloat16(r.y);
      bf16 t2 = __float2bfloat16(r.z), t3 = __float2bfloat16(r.w);
      ushort4 hv;
      hv.x = *reinterpret_cast<unsigned short*>(&t0);
      hv.y = *reinterpret_cast<unsigned short*>(&t1);
      hv.z = *reinterpret_cast<unsigned short*>(&t2);
      hv.w = *reinterpret_cast<unsigned short*>(&t3);
      *reinterpret_cast<ushort4*>(h1 + (size_t)n*HDIM + 4*m) = hv;
    }
  }
}

// ---------------- launch ----------------

extern "C" void kernel_launch(void* const* d_in, const int* in_sizes, int n_in,
                              void* d_out, int out_size, void* d_ws, size_t ws_size,
                              hipStream_t stream){
  const float* node_feat = (const float*)d_in[0];
  const float* W1        = (const float*)d_in[1];
  const float* attn_l1   = (const float*)d_in[2];
  const float* attn_r1   = (const float*)d_in[3];
  const float* b1        = (const float*)d_in[4];
  const float* W2        = (const float*)d_in[5];
  const float* attn_l2   = (const float*)d_in[6];
  const float* attn_r2   = (const float*)d_in[7];
  const float* b2        = (const float*)d_in[8];
  const float* ent_emb   = (const float*)d_in[9];
  const float* rel_emb   = (const float*)d_in[10];
  const float* glob      = (const float*)d_in[11];
  const float* sht       = (const float*)d_in[12];
  const int*  e_src      = (const int*)d_in[13];
  const int*  e_dst      = (const int*)d_in[14];
  const int*  nid        = (const int*)d_in[15];
  const int*  s_tem      = (const int*)d_in[16];
  const int*  r_tem      = (const int*)d_in[17];
  float* out = (float*)d_out;

  char* ws = (char*)d_ws;
  size_t cur_off = 0;
  auto alloc = [&](size_t bytes)->char*{
    char* r = ws + cur_off;
    cur_off += (bytes + 255) & ~(size_t)255;
    return r;
  };
  fp8t*  feat8 = (fp8t*) alloc((size_t)N_NODES*HEADS*HDIM);
  bf16*  nfb   = (bf16*) alloc((size_t)N_NODES*HDIM*2);
  bf16*  h1    = (bf16*) alloc((size_t)N_NODES*HDIM*2);
  float* el4   = (float*)alloc((size_t)N_NODES*4*4);
  float* er4   = (float*)alloc((size_t)N_NODES*4*4);
  bf16*  wt1   = (bf16*) alloc((size_t)HEADS*HDIM*HDIM*2);
  bf16*  wt2   = (bf16*) alloc((size_t)HEADS*HDIM*HDIM*2);
  int*   offs  = (int*)  alloc((size_t)(N_NODES+1)*4);
  int*   cnt   = (int*)  alloc((size_t)N_NODES*4);
  int*   bsum  = (int*)  alloc((size_t)SCAN_NB*4);
  unsigned char* mark = (unsigned char*)alloc((size_t)N_NODES);
  int*   mlist = (int*)  alloc((size_t)N_NODES*4);
  int*   mcnt  = (int*)  alloc(256);
  int*   csr   = (int*)  alloc((size_t)N_EDGES*4);

  // init + fused(hist, weight transpose, node_feat cvt)
  k_init<<<(N_NODES+255)/256, 256, 0, stream>>>(cnt, (int*)mark, mcnt);
  k_misc<<<MISC_NB, 256, 0, stream>>>(e_dst, cnt, W1, W2, wt1, wt2,
                                      node_feat, nfb);

  // scan (2 dispatches) + scatter + mark + list
  k_scan_part<<<SCAN_NB, 256, 0, stream>>>(cnt, bsum);
  k_scan_write<<<SCAN_NB, 256, 0, stream>>>(cnt, bsum, offs);   // also zeroes cnt
  k_scatter<<<(N_EDGES+255)/256, 256, 0, stream>>>(e_src, e_dst, offs, cnt, csr, N_EDGES);
  k_mark<<<BB*LL, 64, 0, stream>>>(nid, offs, csr, mark);
  k_mklist<<<(N_NODES+255)/256, 256, 0, stream>>>(mark, mlist, mcnt);

  dim3 ggrid((N_NODES + 63)/64, HEADS);

  // Layer 1 (agg over marked list only)
  k_gemm<0><<<ggrid, 256, 0, stream>>>(nfb, wt1, attn_l1, attn_r1,
                                       feat8, el4, er4, nullptr, nullptr, N_NODES);
  k_agg<1,0,1><<<N_NODES, 64, 0, stream>>>(feat8, el4, er4, b1, offs, csr,
                                           mlist, mcnt, h1,
                                           nullptr, nullptr, nullptr, nullptr,
                                           nullptr, nullptr, nullptr, N_NODES);

  // Layer 2 (gemm over marked rows; agg fused with assembly)
  k_gemm<1><<<ggrid, 256, 0, stream>>>(h1, wt2, attn_l2, attn_r2,
                                       feat8, el4, er4, mlist, mcnt, N_NODES);
  k_agg<1,1,0><<<BB*LL, 64, 0, stream>>>(feat8, el4, er4, b2, offs, csr,
                                         nid, nullptr, nullptr,
                                         ent_emb, rel_emb, glob, sht,
                                         s_tem, r_tem, out, BB*LL);
}